// Round 1
// 227.915 us; speedup vs baseline: 1.0123x; 1.0123x over previous
//
#include <hip/hip_runtime.h>

// TemporalPSPGate: state_t = ALPHA*state_{t-1} + x_t ; out_t = x_t * sigmoid(state_t)
// x: (T,B,H,N,D) = (16,16,8,256,64) fp32.
//
// Session journal:
// R1: compiler serialized load->use (VGPR=28), kernel 83us.
// R2: 16-deep register prefetch -> kernel ~64us (dur_us 230.7 incl. 2x83us harness fills).
// R3 (this): kernel is pure streaming with ZERO reuse but was using cached
//   loads/stores -> L2/L3 allocate+evict churn on 268 MB of single-touch data.
//   Switch to nontemporal (nt) loads+stores; also replace IEEE 1/(1+e) div
//   (~9 VALU ops) with v_rcp_f32 (absmax headroom is huge).
//   Predicted: kernel 64 -> ~50us, dur_us -> ~215.

#define T_STEPS 16
#define SPATIAL (16LL * 8LL * 256LL * 64LL)   // B*H*N*D = 2,097,152 floats per t
#define VEC4    (SPATIAL / 4)                 // 524,288 float4 slots per t
#define ALPHA_F 0.60653065971263342f          // exp(-1/2)

typedef float f32x4 __attribute__((ext_vector_type(4)));

__global__ __launch_bounds__(256) void
TemporalPSPGate_35613868819159_kernel(const f32x4* __restrict__ x,
                                      f32x4* __restrict__ out) {
    const long long i = (long long)blockIdx.x * 256 + threadIdx.x;  // [0, VEC4)

    // Phase 1: issue all 16 loads back-to-back (16 KB in flight per wave).
    // nt: single-touch stream, don't let it allocate/churn L2/L3.
    f32x4 xv[T_STEPS];
    #pragma unroll
    for (int t = 0; t < T_STEPS; ++t) {
        xv[t] = __builtin_nontemporal_load(x + (long long)t * VEC4 + i);
    }

    // Phase 2: recurrence + gate + store. The state chain is 4-cycle FMA
    // deps; sigmoids/stores are off-chain and pipeline freely.
    f32x4 st = {0.f, 0.f, 0.f, 0.f};
    #pragma unroll
    for (int t = 0; t < T_STEPS; ++t) {
        st = ALPHA_F * st + xv[t];

        f32x4 o;
        #pragma unroll
        for (int c = 0; c < 4; ++c) {
            const float e = __expf(-st[c]);
            o[c] = xv[t][c] * __builtin_amdgcn_rcpf(1.0f + e);
        }
        __builtin_nontemporal_store(o, out + (long long)t * VEC4 + i);
    }
}

extern "C" void kernel_launch(void* const* d_in, const int* in_sizes, int n_in,
                              void* d_out, int out_size, void* d_ws, size_t ws_size,
                              hipStream_t stream) {
    const f32x4* x = (const f32x4*)d_in[0];
    f32x4* out = (f32x4*)d_out;

    const int block = 256;
    const int grid = (int)(VEC4 / block);   // 2048 blocks = 524,288 threads

    TemporalPSPGate_35613868819159_kernel<<<grid, block, 0, stream>>>(x, out);
}